// Round 1
// baseline (903.044 us; speedup 1.0000x reference)
//
#include <hip/hip_runtime.h>

#define NNODE 500000
#define NEDGE 8000000

// ---------------------------------------------------------------------------
// Wf[16][32] = W_gcn[16][48] @ W1[48][32]  (one block, 512 threads)
// ---------------------------------------------------------------------------
__global__ void fuse_w_kernel(const float* __restrict__ Wg,
                              const float* __restrict__ W1,
                              float* __restrict__ Wf) {
    int t = threadIdx.x;          // 0..511
    int r = t >> 5;               // 0..15
    int c = t & 31;               // 0..31
    float s = 0.f;
    #pragma unroll
    for (int k = 0; k < 48; ++k) s += Wg[r * 48 + k] * W1[k * 32 + c];
    Wf[t] = s;
}

// init: deg = 1 (self-loop), agg = 0   (ws is poisoned 0xAA every call)
__global__ void init_kernel(int* __restrict__ deg, float* __restrict__ agg) {
    int t = blockIdx.x * blockDim.x + threadIdx.x;
    if (t < 16 * NNODE) agg[t] = 0.f;
    if (t < NNODE) deg[t] = 1;
}

__global__ void deg_kernel(const int* __restrict__ dst, int* __restrict__ deg) {
    int e = blockIdx.x * blockDim.x + threadIdx.x;
    if (e < NEDGE) atomicAdd(&deg[dst[e]], 1);
}

__global__ void dinv_kernel(const int* __restrict__ deg, float* __restrict__ dinv) {
    int i = blockIdx.x * blockDim.x + threadIdx.x;
    if (i < NNODE) dinv[i] = rsqrtf((float)deg[i]);
}

// scatter: 16 lanes per edge; lane group covers one 64B agg row
__global__ __launch_bounds__(256) void scatter_kernel(
        const int* __restrict__ src, const int* __restrict__ dst,
        const float* __restrict__ xx, const float* __restrict__ dinv,
        float* __restrict__ agg) {
    unsigned t = blockIdx.x * 256u + threadIdx.x;
    unsigned e = t >> 4;
    int c = t & 15;
    if (e < NEDGE) {
        int s = src[e];
        int d = dst[e];
        float v = xx[(size_t)s * 16 + c] * dinv[s];
        atomicAdd(&agg[(size_t)d * 16 + c], v);
    }
}

// epilogue: a = dinv*(agg + x*dinv); t = relu(a@Wf + b1); u = t@W2 + b2; out = x+u
__global__ __launch_bounds__(256) void final_kernel(
        const float* __restrict__ xx, const float* __restrict__ agg,
        const float* __restrict__ dinv, const float* __restrict__ Wf,
        const float* __restrict__ b1, const float* __restrict__ W2,
        const float* __restrict__ b2, float* __restrict__ out) {
    __shared__ float sWf[512];
    __shared__ float sW2[512];
    __shared__ float sb1[32];
    __shared__ float sb2[16];
    int tid = threadIdx.x;
    for (int k = tid; k < 512; k += 256) { sWf[k] = Wf[k]; sW2[k] = W2[k]; }
    if (tid < 32) sb1[tid] = b1[tid];
    if (tid < 16) sb2[tid] = b2[tid];
    __syncthreads();

    int i = blockIdx.x * 256 + tid;
    if (i >= NNODE) return;

    float di = dinv[i];
    const float4* xx4 = (const float4*)(xx + (size_t)i * 16);
    const float4* ag4 = (const float4*)(agg + (size_t)i * 16);
    float x[16], a[16];
    #pragma unroll
    for (int q = 0; q < 4; ++q) {
        float4 xv = xx4[q];
        float4 av = ag4[q];
        x[4 * q + 0] = xv.x; x[4 * q + 1] = xv.y; x[4 * q + 2] = xv.z; x[4 * q + 3] = xv.w;
        a[4 * q + 0] = di * (av.x + xv.x * di);
        a[4 * q + 1] = di * (av.y + xv.y * di);
        a[4 * q + 2] = di * (av.z + xv.z * di);
        a[4 * q + 3] = di * (av.w + xv.w * di);
    }

    float tacc[32];
    #pragma unroll
    for (int j = 0; j < 32; ++j) tacc[j] = sb1[j];
    #pragma unroll
    for (int c = 0; c < 16; ++c) {
        float av = a[c];
        #pragma unroll
        for (int j = 0; j < 32; ++j) tacc[j] += av * sWf[c * 32 + j];
    }
    #pragma unroll
    for (int j = 0; j < 32; ++j) tacc[j] = fmaxf(tacc[j], 0.f);

    float u[16];
    #pragma unroll
    for (int c = 0; c < 16; ++c) u[c] = sb2[c];
    #pragma unroll
    for (int j = 0; j < 32; ++j) {
        float tv = tacc[j];
        #pragma unroll
        for (int c = 0; c < 16; ++c) u[c] += tv * sW2[j * 16 + c];
    }

    float4* o4 = (float4*)(out + (size_t)i * 16);
    #pragma unroll
    for (int q = 0; q < 4; ++q) {
        o4[q] = make_float4(x[4 * q + 0] + u[4 * q + 0],
                            x[4 * q + 1] + u[4 * q + 1],
                            x[4 * q + 2] + u[4 * q + 2],
                            x[4 * q + 3] + u[4 * q + 3]);
    }
}

extern "C" void kernel_launch(void* const* d_in, const int* in_sizes, int n_in,
                              void* d_out, int out_size, void* d_ws, size_t ws_size,
                              hipStream_t stream) {
    const float* xx   = (const float*)d_in[0];
    const int*   edge = (const int*)d_in[1];   // [2, E]: row0 = src, row1 = dst
    const float* Wg   = (const float*)d_in[2];
    const float* W1   = (const float*)d_in[3];
    const float* b1   = (const float*)d_in[4];
    const float* W2   = (const float*)d_in[5];
    const float* b2   = (const float*)d_in[6];
    float* out = (float*)d_out;

    const int* srcI = edge;
    const int* dstI = edge + NEDGE;

    // workspace layout (floats): deg[N] | dinv[N] | agg[16N] | Wf[512]
    float* ws   = (float*)d_ws;
    int*   deg  = (int*)ws;
    float* dinv = ws + NNODE;
    float* agg  = ws + 2 * (size_t)NNODE;
    float* Wf   = ws + 18 * (size_t)NNODE;

    hipLaunchKernelGGL(fuse_w_kernel, dim3(1), dim3(512), 0, stream, Wg, W1, Wf);

    int initN = 16 * NNODE;
    hipLaunchKernelGGL(init_kernel, dim3((initN + 255) / 256), dim3(256), 0, stream,
                       deg, agg);

    hipLaunchKernelGGL(deg_kernel, dim3((NEDGE + 255) / 256), dim3(256), 0, stream,
                       dstI, deg);

    hipLaunchKernelGGL(dinv_kernel, dim3((NNODE + 255) / 256), dim3(256), 0, stream,
                       deg, dinv);

    unsigned scatterT = 16u * NEDGE;   // 128M threads, 16 lanes per edge
    hipLaunchKernelGGL(scatter_kernel, dim3(scatterT / 256), dim3(256), 0, stream,
                       srcI, dstI, xx, dinv, agg);

    hipLaunchKernelGGL(final_kernel, dim3((NNODE + 255) / 256), dim3(256), 0, stream,
                       xx, agg, dinv, Wf, b1, W2, b2, out);
}